// Round 7
// baseline (411.683 us; speedup 1.0000x reference)
//
#include <hip/hip_runtime.h>
#include <hip/hip_bf16.h>

#define NN 50000
#define NE 1600000
#define DIM 128
#define NG 64
#define EPSV 1e-5f
#define NCHUNK 49   // ceil(50000/1024)
#define RUN 4       // nodes per wave in pool kernel (segment aggregation)
#define NXCD 8
#define SHARD_COLS (NN / NXCD)   // 6250
#define FILL_CHUNKS 256          // edge chunks; grid = 8 * FILL_CHUNKS

typedef __attribute__((ext_vector_type(8))) __bf16 bf16x8;
typedef __attribute__((ext_vector_type(2))) __bf16 bf16x2;
typedef __attribute__((ext_vector_type(16))) float f32x16;

// ---------------- CSR build ----------------

__global__ void count_kernel(const int* __restrict__ ecol, int* __restrict__ cnt) {
    int e = blockIdx.x * 256 + threadIdx.x;
    if (e < NE) atomicAdd(&cnt[ecol[e]], 1);
}

__global__ void scan_chunk(const int* __restrict__ cnt, int* __restrict__ excl,
                           int* __restrict__ csum) {
    __shared__ int lds[256];
    int t = threadIdx.x;
    int base = blockIdx.x * 1024 + t * 4;
    int v0 = (base + 0 < NN) ? cnt[base + 0] : 0;
    int v1 = (base + 1 < NN) ? cnt[base + 1] : 0;
    int v2 = (base + 2 < NN) ? cnt[base + 2] : 0;
    int v3 = (base + 3 < NN) ? cnt[base + 3] : 0;
    int s = v0 + v1 + v2 + v3;
    lds[t] = s;
    __syncthreads();
    for (int off = 1; off < 256; off <<= 1) {
        int x = (t >= off) ? lds[t - off] : 0;
        __syncthreads();
        lds[t] += x;
        __syncthreads();
    }
    int run = lds[t] - s;           // exclusive prefix within chunk
    if (t == 255) csum[blockIdx.x] = lds[t];
    if (base + 0 < NN) excl[base + 0] = run; run += v0;
    if (base + 1 < NN) excl[base + 1] = run; run += v1;
    if (base + 2 < NN) excl[base + 2] = run; run += v2;
    if (base + 3 < NN) excl[base + 3] = run;
}

__global__ void scan_tail(const int* __restrict__ csum, int* __restrict__ coff, int nch) {
    int l = threadIdx.x;
    int v = (l < nch) ? csum[l] : 0;
    int s = v;
    for (int o = 1; o < 64; o <<= 1) {
        int x = __shfl_up(s, o);
        if (l >= o) s += x;
    }
    if (l < nch) coff[l] = s - v;   // exclusive chunk offsets
}

__global__ void fixup_kernel(int* __restrict__ row_ptr, const int* __restrict__ coff,
                             const int* __restrict__ cnt, float* __restrict__ dinv,
                             int* __restrict__ cursor) {
    int n = blockIdx.x * 256 + threadIdx.x;
    if (n < NN) {
        int rp = row_ptr[n] + coff[n >> 10];
        row_ptr[n] = rp;
        cursor[n] = rp;
        dinv[n] = rsqrtf((float)(cnt[n] + 1));   // +1 for self-loop
    }
    if (n == 0) row_ptr[NN] = NE;
}

// XCD-sharded scatter: block b handles col-shard (b&7) over edge-chunk (b>>3).
__global__ void fill_kernel(const int* __restrict__ erow, const int* __restrict__ ecol,
                            int* __restrict__ cursor, int* __restrict__ esrc) {
    const int shard = blockIdx.x & (NXCD - 1);
    const int chunk = blockIdx.x >> 3;
    const int lo = shard * SHARD_COLS;
    const int hi = lo + SHARD_COLS;       // NN divisible by 8
    for (int e = chunk * 256 + threadIdx.x; e < NE; e += FILL_CHUNKS * 256) {
        const int c = ecol[e];
        if (c >= lo && c < hi) {
            int pos = atomicAdd(&cursor[c], 1);
            esrc[pos] = erow[e];
        }
    }
}

// fold bias+BN into per-col scale/shift:  out = acc*scale + shift
__global__ void bn_prep_kernel(const float* __restrict__ b1, const float* __restrict__ g1,
                               const float* __restrict__ be1, const float* __restrict__ rm1,
                               const float* __restrict__ rv1,
                               const float* __restrict__ b2, const float* __restrict__ g2,
                               const float* __restrict__ be2, const float* __restrict__ rm2,
                               const float* __restrict__ rv2,
                               float* __restrict__ sc1, float* __restrict__ sh1,
                               float* __restrict__ sc2, float* __restrict__ sh2) {
    int c = threadIdx.x;
    if (c < DIM) {
        float s1 = g1[c] * rsqrtf(rv1[c] + EPSV);
        sc1[c] = s1;
        sh1[c] = (b1[c] - rm1[c]) * s1 + be1[c];
        float s2 = g2[c] * rsqrtf(rv2[c] + EPSV);
        sc2[c] = s2;
        sh2[c] = (b2[c] - rm2[c]) * s2 + be2[c];
    }
}

// ---------------- dense: (h @ W) * dinv[row] -> bf16 table ----------------

__device__ __forceinline__ bf16x8 load8(const float* p) {
    float4 lo = ((const float4*)p)[0], hi = ((const float4*)p)[1];
    bf16x8 a;
    a[0] = (__bf16)lo.x; a[1] = (__bf16)lo.y; a[2] = (__bf16)lo.z; a[3] = (__bf16)lo.w;
    a[4] = (__bf16)hi.x; a[5] = (__bf16)hi.y; a[6] = (__bf16)hi.z; a[7] = (__bf16)hi.w;
    return a;
}
__device__ __forceinline__ bf16x8 load8(const __bf16* p) {
    return *(const bf16x8*)p;
}

template <typename T>
__global__ void __launch_bounds__(256) matmul_kernel(const T* __restrict__ h,
                                                     const float* __restrict__ W,
                                                     const float* __restrict__ dinv,
                                                     __bf16* __restrict__ t) {
    const int wave = threadIdx.x >> 6;
    const int lane = threadIdx.x & 63;
    const int col = wave * 32 + (lane & 31);
    const int khalf = (lane >> 5) * 8;   // 0 or 8

    bf16x8 b[8];
#pragma unroll
    for (int kc = 0; kc < 8; kc++) {
#pragma unroll
        for (int j = 0; j < 8; j++) {
            b[kc][j] = (__bf16)W[(kc * 16 + khalf + j) * DIM + col];
        }
    }

    const int ntiles = (NN + 31) / 32;
    for (int tile = blockIdx.x; tile < ntiles; tile += gridDim.x) {
        const int arow = tile * 32 + (lane & 31);
        const int arow_c = (arow < NN) ? arow : (NN - 1);  // clamped load; bad rows not stored
        f32x16 acc = {};
#pragma unroll
        for (int kc = 0; kc < 8; kc++) {
            bf16x8 a = load8(h + (size_t)arow_c * DIM + kc * 16 + khalf);
            acc = __builtin_amdgcn_mfma_f32_32x32x16_bf16(a, b[kc], acc, 0, 0, 0);
        }
#pragma unroll
        for (int r = 0; r < 16; r++) {
            int orow = tile * 32 + (r & 3) + 8 * (r >> 2) + 4 * (lane >> 5);
            if (orow < NN) t[(size_t)orow * DIM + col] = (__bf16)(acc[r] * dinv[orow]);
        }
    }
}

// ---------------- sparse: pull-gather, TWO nodes per wave ----------------
// Lane handles cols {2*lane, 2*lane+1}. Two nodes' edge lists are walked
// with interleaved 8-edge bursts, so up to 16 independent 256B table-row
// loads are in flight per wave (vs 8 with one node/wave). beg/end are
// wave-uniform (SGPR) so the esrc index loads are scalar.

__device__ __forceinline__ void gather2(
    const unsigned int* __restrict__ t32, const int* __restrict__ esrc,
    int beg0, int end0, int beg1, int end1, int lane,
    float& ax0, float& ay0, float& ax1, float& ay1) {
    int e0 = beg0, e1 = beg1;
    while (e0 < end0 || e1 < end1) {
        const bool a0 = e0 < end0, a1 = e1 < end1;
        int s0[8], s1[8];
        float w0[8], w1[8];
        unsigned int u0[8], u1[8];
        if (a0) {
#pragma unroll
            for (int i = 0; i < 8; i++) {
                const bool ok = (e0 + i) < end0;
                s0[i] = esrc[ok ? (e0 + i) : beg0];
                w0[i] = ok ? 1.f : 0.f;
            }
#pragma unroll
            for (int i = 0; i < 8; i++) u0[i] = t32[(size_t)s0[i] * 64 + lane];
        }
        if (a1) {
#pragma unroll
            for (int i = 0; i < 8; i++) {
                const bool ok = (e1 + i) < end1;
                s1[i] = esrc[ok ? (e1 + i) : beg1];
                w1[i] = ok ? 1.f : 0.f;
            }
#pragma unroll
            for (int i = 0; i < 8; i++) u1[i] = t32[(size_t)s1[i] * 64 + lane];
        }
        if (a0) {
#pragma unroll
            for (int i = 0; i < 8; i++) {
                ax0 = fmaf(__uint_as_float(u0[i] << 16), w0[i], ax0);
                ay0 = fmaf(__uint_as_float(u0[i] & 0xffff0000u), w0[i], ay0);
            }
            e0 += 8;
        }
        if (a1) {
#pragma unroll
            for (int i = 0; i < 8; i++) {
                ax1 = fmaf(__uint_as_float(u1[i] << 16), w1[i], ax1);
                ay1 = fmaf(__uint_as_float(u1[i] & 0xffff0000u), w1[i], ay1);
            }
            e1 += 8;
        }
    }
}

__global__ void __launch_bounds__(256) gather_bn_kernel(
    const unsigned int* __restrict__ t32, const int* __restrict__ row_ptr,
    const int* __restrict__ esrc, const float* __restrict__ dinv,
    const float* __restrict__ scale, const float* __restrict__ shift,
    __bf16* __restrict__ out) {
    const int lane = threadIdx.x & 63;
    const int pair = __builtin_amdgcn_readfirstlane(blockIdx.x * 4 + (threadIdx.x >> 6));
    const int n0 = pair * 2;            // NN even -> n0+1 always valid
    if (n0 >= NN) return;
    const int n1 = n0 + 1;
    const int b0 = row_ptr[n0], m = row_ptr[n1], e1 = row_ptr[n1 + 1];
    float ax0 = 0.f, ay0 = 0.f, ax1 = 0.f, ay1 = 0.f;
    gather2(t32, esrc, b0, m, m, e1, lane, ax0, ay0, ax1, ay1);
    {   // self loops (weight 1; dinv[n] applied below)
        const unsigned int u0 = t32[(size_t)n0 * 64 + lane];
        const unsigned int u1 = t32[(size_t)n1 * 64 + lane];
        ax0 += __uint_as_float(u0 << 16);
        ay0 += __uint_as_float(u0 & 0xffff0000u);
        ax1 += __uint_as_float(u1 << 16);
        ay1 += __uint_as_float(u1 & 0xffff0000u);
    }
    const float dv0 = dinv[n0], dv1 = dinv[n1];
    const int c0 = lane * 2, c1 = c0 + 1;
    const float sx = scale[c0], sy = scale[c1];
    const float hx = shift[c0], hy = shift[c1];
    bf16x2 o0, o1;
    o0[0] = (__bf16)fmaxf(fmaf(ax0, dv0 * sx, hx), 0.f);
    o0[1] = (__bf16)fmaxf(fmaf(ay0, dv0 * sy, hy), 0.f);
    o1[0] = (__bf16)fmaxf(fmaf(ax1, dv1 * sx, hx), 0.f);
    o1[1] = (__bf16)fmaxf(fmaf(ay1, dv1 * sy, hy), 0.f);
    *(bf16x2*)(out + (size_t)n0 * DIM + c0) = o0;
    *(bf16x2*)(out + (size_t)n1 * DIM + c0) = o1;
}

// Pool: batch is SORTED -> segment reduction. 4 nodes per wave processed as
// two interleaved pairs; flush atomics only at graph boundary / run end.

__global__ void __launch_bounds__(256) gather_pool_kernel(
    const unsigned int* __restrict__ t32, const int* __restrict__ row_ptr,
    const int* __restrict__ esrc, const float* __restrict__ dinv,
    const float* __restrict__ bias, const int* __restrict__ batch,
    float* __restrict__ out) {
    const int lane = threadIdx.x & 63;
    const int wid = __builtin_amdgcn_readfirstlane(blockIdx.x * 4 + (threadIdx.x >> 6));
    const int n0 = wid * RUN;           // NN % RUN == 0 -> all 4 valid
    if (n0 >= NN) return;
    const int c0 = lane * 2, c1 = c0 + 1;
    const float bx = bias[c0], by = bias[c1];

    float ax[RUN], ay[RUN];
#pragma unroll
    for (int p = 0; p < RUN / 2; p++) {
        const int na = n0 + 2 * p, nb = na + 1;
        const int ba = row_ptr[na], mm = row_ptr[nb], eb = row_ptr[nb + 1];
        float x0 = 0.f, y0 = 0.f, x1 = 0.f, y1 = 0.f;
        gather2(t32, esrc, ba, mm, mm, eb, lane, x0, y0, x1, y1);
        const unsigned int ua = t32[(size_t)na * 64 + lane];
        const unsigned int ub = t32[(size_t)nb * 64 + lane];
        x0 += __uint_as_float(ua << 16);
        y0 += __uint_as_float(ua & 0xffff0000u);
        x1 += __uint_as_float(ub << 16);
        y1 += __uint_as_float(ub & 0xffff0000u);
        ax[2 * p] = x0; ay[2 * p] = y0;
        ax[2 * p + 1] = x1; ay[2 * p + 1] = y1;
    }

    float rx = 0.f, ry = 0.f;
    int g = batch[n0];
#pragma unroll
    for (int j = 0; j < RUN; j++) {
        const int n = n0 + j;
        const float dv = dinv[n];
        const int gn = batch[n];
        if (gn != g) {   // graph boundary: flush previous segment (uniform branch)
            atomicAdd(out + (size_t)g * DIM + c0, rx);
            atomicAdd(out + (size_t)g * DIM + c1, ry);
            rx = 0.f; ry = 0.f; g = gn;
        }
        rx += fmaf(ax[j], dv, bx);
        ry += fmaf(ay[j], dv, by);
    }
    atomicAdd(out + (size_t)g * DIM + c0, rx);
    atomicAdd(out + (size_t)g * DIM + c1, ry);
}

// ---------------- launch ----------------

extern "C" void kernel_launch(void* const* d_in, const int* in_sizes, int n_in,
                              void* d_out, int out_size, void* d_ws, size_t ws_size,
                              hipStream_t stream) {
    const float* x    = (const float*)d_in[0];
    const int*   ei   = (const int*)d_in[1];
    const int*   batch= (const int*)d_in[2];
    const float* W1 = (const float*)d_in[3];
    const float* b1 = (const float*)d_in[4];
    const float* W2 = (const float*)d_in[5];
    const float* b2 = (const float*)d_in[6];
    const float* W3 = (const float*)d_in[7];
    const float* b3 = (const float*)d_in[8];
    const float* g1 = (const float*)d_in[9];
    const float* be1= (const float*)d_in[10];
    const float* rm1= (const float*)d_in[11];
    const float* rv1= (const float*)d_in[12];
    const float* g2 = (const float*)d_in[13];
    const float* be2= (const float*)d_in[14];
    const float* rm2= (const float*)d_in[15];
    const float* rv2= (const float*)d_in[16];
    const int* erow = ei;
    const int* ecol = ei + NE;

    char* ws = (char*)d_ws;
    size_t off = 0;
    auto alloc = [&](size_t bytes) -> void* {
        void* p = ws + off;
        off = (off + bytes + 255) & ~(size_t)255;
        return p;
    };
    int*    cnt     = (int*)alloc(NN * sizeof(int));
    int*    row_ptr = (int*)alloc((NN + 1) * sizeof(int));
    int*    cursor  = (int*)alloc(NN * sizeof(int));
    int*    csum    = (int*)alloc(64 * sizeof(int));
    int*    coff    = (int*)alloc(64 * sizeof(int));
    float*  dinv    = (float*)alloc(NN * sizeof(float));
    int*    esrc    = (int*)alloc(NE * sizeof(int));
    __bf16* tbuf    = (__bf16*)alloc((size_t)NN * DIM * sizeof(__bf16));
    __bf16* hbuf    = (__bf16*)alloc((size_t)NN * DIM * sizeof(__bf16));
    float*  sc1     = (float*)alloc(DIM * sizeof(float));
    float*  sh1     = (float*)alloc(DIM * sizeof(float));
    float*  sc2     = (float*)alloc(DIM * sizeof(float));
    float*  sh2     = (float*)alloc(DIM * sizeof(float));

    hipMemsetAsync(cnt, 0, NN * sizeof(int), stream);
    hipMemsetAsync(d_out, 0, NG * DIM * sizeof(float), stream);

    bn_prep_kernel<<<1, 128, 0, stream>>>(b1, g1, be1, rm1, rv1,
                                          b2, g2, be2, rm2, rv2,
                                          sc1, sh1, sc2, sh2);
    count_kernel<<<(NE + 255) / 256, 256, 0, stream>>>(ecol, cnt);
    scan_chunk<<<NCHUNK, 256, 0, stream>>>(cnt, row_ptr, csum);
    scan_tail<<<1, 64, 0, stream>>>(csum, coff, NCHUNK);
    fixup_kernel<<<(NN + 255) / 256, 256, 0, stream>>>(row_ptr, coff, cnt, dinv, cursor);
    fill_kernel<<<NXCD * FILL_CHUNKS, 256, 0, stream>>>(erow, ecol, cursor, esrc);

    const unsigned int* t32 = (const unsigned int*)tbuf;
    const int npairs = NN / 2;
    const int nblk_bn = (npairs + 3) / 4;
    const int nwaves_pool = (NN + RUN - 1) / RUN;
    const int nblk_pool = (nwaves_pool + 3) / 4;

    matmul_kernel<float><<<512, 256, 0, stream>>>(x, W1, dinv, tbuf);
    gather_bn_kernel<<<nblk_bn, 256, 0, stream>>>(t32, row_ptr, esrc, dinv,
                                                  sc1, sh1, hbuf);
    matmul_kernel<__bf16><<<512, 256, 0, stream>>>(hbuf, W2, dinv, tbuf);
    gather_bn_kernel<<<nblk_bn, 256, 0, stream>>>(t32, row_ptr, esrc, dinv,
                                                  sc2, sh2, hbuf);
    matmul_kernel<__bf16><<<512, 256, 0, stream>>>(hbuf, W3, dinv, tbuf);
    gather_pool_kernel<<<nblk_pool, 256, 0, stream>>>(t32, row_ptr, esrc, dinv,
                                                      b3, batch, (float*)d_out);
}